// Round 9
// baseline (225.972 us; speedup 1.0000x reference)
//
#include <hip/hip_runtime.h>
#include <math.h>

#define CH    64
#define WW    192
#define HH    192
#define HWSZ  (192*192)
#define KK    49
#define ROWP  68   // padded fp32 LDS row (dwords)
#define SROW  72   // f16 row stride in shorts (144B)
#define C3ROW 72   // conv3 staged px stride (shorts)
#define OROW  136  // k_out staged px stride (shorts, 128ch + 8 pad)

typedef __attribute__((ext_vector_type(8))) short     s16x8;
typedef __attribute__((ext_vector_type(8))) _Float16  h16x8;  // 8 f16 = 4 VGPR
typedef __attribute__((ext_vector_type(2))) _Float16  h16x2;
typedef __attribute__((ext_vector_type(2))) __fp16    fp16x2; // cvt_pkrtz result type
typedef __attribute__((ext_vector_type(4))) float     f32x4;

__device__ __forceinline__ unsigned short f2h(float f) {
    union { _Float16 h; unsigned short s; } u; u.h = (_Float16)f;  // RNE
    return u.s;
}

// pack two floats to f16x2 (RTZ, single v_cvt_pkrtz_f16_f32)
__device__ __forceinline__ unsigned pkh(float lo, float hi) {
    union { fp16x2 h; unsigned u; } v;
    v.h = __builtin_amdgcn_cvt_pkrtz(lo, hi);
    return v.u;
}

// broadcast one float into packed f16x2 (for pk_fma weights)
__device__ __forceinline__ h16x2 cvt2h(float a) {
    union { fp16x2 h; h16x2 o; } v;
    v.h = __builtin_amdgcn_cvt_pkrtz(a, a);
    return v.o;
}

__device__ __forceinline__ h16x2 as_h2(unsigned u) {
    union { unsigned u; h16x2 h; } v; v.u = u; return v.h;
}

__device__ __forceinline__ unsigned as_u(h16x2 h) {
    union { h16x2 h; unsigned u; } v; v.h = h; return v.u;
}

// ---------------------------------------------------------------------------
// k_prep (grid 49 x 256): krT + A-fragment packs (wA, w2A, wpoA, wpiA), f16
// ---------------------------------------------------------------------------
__device__ const float c_cos8[8] = {
    1.f, 0.70710678118654752f, 0.f, -0.70710678118654752f,
   -1.f, -0.70710678118654752f, 0.f, 0.70710678118654752f };

__global__ __launch_bounds__(256) void k_prep(
    const float* __restrict__ fw,   // [64,1,1,8,5]
    const float* __restrict__ wd,   // [64,64,7,7]
    const float* __restrict__ w2,   // [64,64,3,3]
    const float* __restrict__ wc1,  // [64,64,1,1]
    const float* __restrict__ wpo,  // [128,128]
    const float* __restrict__ wpi,  // [64,64]
    float* __restrict__ krT,        // [64 uv][64 c]
    short* __restrict__ wA,         // [49*8*512]
    short* __restrict__ w2A,        // [9*8*512]
    short* __restrict__ wpoA,       // [32*512]
    short* __restrict__ wpiA)       // [8*512]
{
    int tid = blockIdx.x * blockDim.x + threadIdx.x;
    int nt  = gridDim.x * blockDim.x;
    for (int t = tid; t < 64 * 64; t += nt) {
        int uv = t >> 6, c = t & 63;
        int u = uv >> 3, v = uv & 7;
        float acc = 0.f;
        for (int ky = 0; ky < 8; ky++)
            for (int kx = 0; kx < 8; kx++) {
                float wv = (kx <= 4) ? fw[c * 40 + ky * 5 + kx]
                                     : fw[c * 40 + ((8 - ky) & 7) * 5 + (8 - kx)];
                acc += wv * c_cos8[(ky * u + kx * v) & 7];
            }
        krT[uv * 64 + c] = acc * (1.f / 64.f);
    }
    for (int t = tid; t < 9 * 4096; t += nt) {
        int tap = t / 4096, rem = t & 4095;
        int o = rem >> 6, c = rem & 63;
        float v = w2[(o * 64 + c) * 9 + tap];
        int fi = tap * 8 + (o >> 4) * 2 + (c >> 5);
        int ln = ((c >> 3) & 3) * 16 + (o & 15);
        w2A[fi * 512 + ln * 8 + (c & 7)] = (short)f2h(v);
    }
    for (int t = tid; t < 128 * 128; t += nt) {
        int o = t >> 7, c = t & 127;
        int fi = (o >> 4) * 4 + (c >> 5);
        int ln = ((c >> 3) & 3) * 16 + (o & 15);
        wpoA[fi * 512 + ln * 8 + (c & 7)] = (short)f2h(wpo[t]);
    }
    for (int t = tid; t < 64 * 64; t += nt) {
        int o = t >> 6, c = t & 63;
        int fi = (o >> 4) * 2 + (c >> 5);
        int ln = ((c >> 3) & 3) * 16 + (o & 15);
        wpiA[fi * 512 + ln * 8 + (c & 7)] = (short)f2h(wpi[t]);
    }

    // ---- fold wc1 @ wd + pack: one block per tap k ----
    __shared__ float wdk [64 * ROWP];
    __shared__ float wc1s[64 * ROWP];
    int k = blockIdx.x;
    int t = threadIdx.x;
#pragma unroll
    for (int r = 0; r < 16; r++) {
        int idx = t + r * 256;
        int o = idx >> 6, c = idx & 63;
        wdk [o * ROWP + c] = wd[(o * 64 + c) * KK + k];
        wc1s[o * ROWP + c] = wc1[o * 64 + c];
    }
    __syncthreads();

    int ot = (t >> 4) * 4, cb = (t & 15) * 4;
    float a[4][4];
#pragma unroll
    for (int i = 0; i < 4; i++)
#pragma unroll
        for (int j = 0; j < 4; j++) a[i][j] = 0.f;
    for (int o = 0; o < 64; o++) {
        float wv_[4], sv_[4];
#pragma unroll
        for (int i = 0; i < 4; i++) wv_[i] = wc1s[(ot + i) * ROWP + o];
#pragma unroll
        for (int j = 0; j < 4; j++) sv_[j] = wdk[o * ROWP + cb + j];
#pragma unroll
        for (int i = 0; i < 4; i++)
#pragma unroll
            for (int j = 0; j < 4; j++) a[i][j] += wv_[i] * sv_[j];
    }
#pragma unroll
    for (int i = 0; i < 4; i++)
#pragma unroll
        for (int j = 0; j < 4; j++) {
            int o2 = ot + i, c = cb + j;
            int tt = o2 >> 4, m = o2 & 15;
            int kt = c >> 5, q = (c >> 3) & 3, jj = c & 7;
            int ln = q * 16 + m;
            wA[(k * 8 + tt * 2 + kt) * 512 + ln * 8 + jj] = (short)f2h(a[i][j]);
        }
}

// ---------------------------------------------------------------------------
// k_trans: enc [c][p] (fp32) -> encH [p][c] (f16) -- halves gather bytes
// ---------------------------------------------------------------------------
__global__ __launch_bounds__(256) void k_trans(
    const float* __restrict__ enc, unsigned short* __restrict__ encH)
{
    __shared__ float s[64 * 65];
    int t = threadIdx.x;
    int base = blockIdx.x * 64;
#pragma unroll
    for (int r = 0; r < 16; r++) {
        int idx = t + r * 256;
        int p = idx & 63, c = idx >> 6;
        s[p * 65 + c] = enc[c * HWSZ + base + p];
    }
    __syncthreads();
#pragma unroll
    for (int r = 0; r < 8; r++) {
        int idx = t + r * 256;             // 2048 pair-units
        int pr = idx & 31, p = idx >> 5;   // pair 0..31, px 0..63
        ((unsigned*)encH)[(base + p) * 32 + pr] =
            pkh(s[p * 65 + 2 * pr], s[p * 65 + 2 * pr + 1]);
    }
}

// ---------------------------------------------------------------------------
// k_deform R15: R12 structure (quad gather map, f16 blend, wave-private
// bounce) + CROSS-TAP SOFTWARE PIPELINE. Ping-pong corner register sets:
// tap k+1's 8 corner loads issue BEFORE tap k's blend consumes set k, so
// the L2 gather latency hides under one full tap of compute (counted vmcnt
// instead of a drain every iteration). R8..R14 established wall time is
// invariant to VALU work and bound by per-iteration exposed latency.
// Offsets roll two taps ahead. Cost: +36 VGPR for the second set.
// ---------------------------------------------------------------------------
#define REDW 20   // reduction row stride (floats): 80B, 16B-aligned

// compute bilinear weights + issue the 8 corner loads for tap KK_ into the
// named register set (A00..C11 are variables of the caller)
#define ISSUE_TAP(KK_, DY_, DX_, MM_, A00_, A01_, A10_, A11_, C0_, C1_, C2_, C3_) \
    do {                                                                       \
        int ky_ = (KK_) / 7, kx_ = (KK_) % 7;                                  \
        float y_ = (float)(gy  - 3 + ky_) + (DY_);                             \
        float x_ = (float)(sgx - 3 + kx_) + (DX_);                             \
        float y0f_ = floorf(y_), x0f_ = floorf(x_);                            \
        float wy_ = y_ - y0f_, wx_ = x_ - x0f_;                                \
        int iy0_ = (int)y0f_, ix0_ = (int)x0f_;                                \
        int iy1_ = iy0_ + 1, ix1_ = ix0_ + 1;                                  \
        bool vy0_ = (iy0_ >= 0) & (iy0_ < HH);                                 \
        bool vy1_ = (iy1_ >= 0) & (iy1_ < HH);                                 \
        bool vx0_ = (ix0_ >= 0) & (ix0_ < WW);                                 \
        bool vx1_ = (ix1_ >= 0) & (ix1_ < WW);                                 \
        int iy0c_ = min(max(iy0_, 0), HH - 1), iy1c_ = min(max(iy1_, 0), HH - 1); \
        int ix0c_ = min(max(ix0_, 0), WW - 1), ix1c_ = min(max(ix1_, 0), WW - 1); \
        A00_ = (vy0_ & vx0_) ? (1.f - wy_) * (1.f - wx_) * (MM_) : 0.f;        \
        A01_ = (vy0_ & vx1_) ? (1.f - wy_) * wx_ * (MM_) : 0.f;                \
        A10_ = (vy1_ & vx0_) ? wy_ * (1.f - wx_) * (MM_) : 0.f;                \
        A11_ = (vy1_ & vx1_) ? wy_ * wx_ * (MM_) : 0.f;                        \
        const unsigned short* p00_ = encH + (iy0c_ * WW + ix0c_) * 64 + g * 16; \
        const unsigned short* p01_ = encH + (iy0c_ * WW + ix1c_) * 64 + g * 16; \
        const unsigned short* p10_ = encH + (iy1c_ * WW + ix0c_) * 64 + g * 16; \
        const unsigned short* p11_ = encH + (iy1c_ * WW + ix1c_) * 64 + g * 16; \
        C0_[0] = *(const uint4*)p00_;  C0_[1] = *(const uint4*)(p00_ + 8);     \
        C1_[0] = *(const uint4*)p01_;  C1_[1] = *(const uint4*)(p01_ + 8);     \
        C2_[0] = *(const uint4*)p10_;  C2_[1] = *(const uint4*)(p10_ + 8);     \
        C3_[0] = *(const uint4*)p11_;  C3_[1] = *(const uint4*)(p11_ + 8);     \
    } while (0)

// consume one tap's register set: A-frag loads + packed-f16 blend + bounce +
// ds_read + 8 MFMAs
#define CONSUME_TAP(KK_, A00_, A01_, A10_, A11_, C0_, C1_, C2_, C3_)           \
    do {                                                                       \
        h16x8 af_[8];                                                          \
        _Pragma("unroll")                                                      \
        for (int f = 0; f < 8; f++)                                            \
            af_[f] = *(const h16x8*)&wA[((KK_) * 8 + f) * 512 + lane * 8];     \
        h16x2 w00_ = cvt2h(A00_), w01_ = cvt2h(A01_);                          \
        h16x2 w10_ = cvt2h(A10_), w11_ = cvt2h(A11_);                          \
        unsigned c00_[8] = {C0_[0].x, C0_[0].y, C0_[0].z, C0_[0].w,            \
                            C0_[1].x, C0_[1].y, C0_[1].z, C0_[1].w};           \
        unsigned c01_[8] = {C1_[0].x, C1_[0].y, C1_[0].z, C1_[0].w,            \
                            C1_[1].x, C1_[1].y, C1_[1].z, C1_[1].w};           \
        unsigned c10_[8] = {C2_[0].x, C2_[0].y, C2_[0].z, C2_[0].w,            \
                            C2_[1].x, C2_[1].y, C2_[1].z, C2_[1].w};           \
        unsigned c11_[8] = {C3_[0].x, C3_[0].y, C3_[0].z, C3_[0].w,            \
                            C3_[1].x, C3_[1].y, C3_[1].z, C3_[1].w};           \
        unsigned pk_[8];                                                       \
        _Pragma("unroll")                                                      \
        for (int j = 0; j < 8; j++) {                                          \
            h16x2 r_ = as_h2(c00_[j]) * w00_;                                  \
            r_ = as_h2(c01_[j]) * w01_ + r_;                                   \
            r_ = as_h2(c10_[j]) * w10_ + r_;                                   \
            r_ = as_h2(c11_[j]) * w11_ + r_;                                   \
            pk_[j] = as_u(r_);                                                 \
        }                                                                      \
        *(uint4*)&smw[sp * SROW + g * 16]     = make_uint4(pk_[0], pk_[1], pk_[2], pk_[3]); \
        *(uint4*)&smw[sp * SROW + g * 16 + 8] = make_uint4(pk_[4], pk_[5], pk_[6], pk_[7]); \
        h16x8 b0_ = *(const h16x8*)&smw[n * SROW +  0 + q * 8];                \
        h16x8 b1_ = *(const h16x8*)&smw[n * SROW + 32 + q * 8];                \
        _Pragma("unroll")                                                      \
        for (int ot = 0; ot < 4; ot++) {                                       \
            acc[ot] = __builtin_amdgcn_mfma_f32_16x16x32_f16(af_[ot * 2],     b0_, acc[ot], 0, 0, 0); \
            acc[ot] = __builtin_amdgcn_mfma_f32_16x16x32_f16(af_[ot * 2 + 1], b1_, acc[ot], 0, 0, 0); \
        }                                                                      \
    } while (0)

#define LOAD_OFF(J_)                                                           \
    do {                                                                       \
        if ((J_) < kend) {                                                     \
            dy = off[(2 * (J_)) * HWSZ + gp_s];                                \
            dx = off[(2 * (J_) + 1) * HWSZ + gp_s];                            \
            mm = msk[(J_) * HWSZ + gp_s];                                      \
        }                                                                      \
    } while (0)

__global__ __launch_bounds__(256) void k_deform(
    const unsigned short* __restrict__ encH, const float* __restrict__ off,
    const float* __restrict__ msk, const short* __restrict__ wA,
    float* __restrict__ rev)
{
    __shared__ __align__(16) short sm[4][16 * SROW];   // 9216 B bounce
    __shared__ __align__(16) float red[2 * 64 * REDW]; // 10240 B reduction

    int t = threadIdx.x;
    int lane = t & 63, w = t >> 6;
    int b = blockIdx.x;
    int xcd = b & 7, blk = b >> 3;          // 288 strips per xcd band
    int gy  = xcd * 24 + blk / 12;
    int gx0 = (blk % 12) * 16;

    int sp = lane >> 2, g = lane & 3;       // gather map: quad-coalesced
    int sgx  = gx0 + sp;
    int gp_s = gy * WW + sgx;
    int n = lane & 15, q = lane >> 4;       // B-frag read map
    short* smw = &sm[w][0];

    f32x4 acc[4];
#pragma unroll
    for (int ot = 0; ot < 4; ot++) acc[ot] = (f32x4){0.f, 0.f, 0.f, 0.f};

    int kstart = (w == 0) ? 0 : 13 + (w - 1) * 12;
    int kend   = (w == 0) ? 13 : kstart + 12;

    float dy = off[(2 * kstart) * HWSZ + gp_s];
    float dx = off[(2 * kstart + 1) * HWSZ + gp_s];
    float mm = msk[kstart * HWSZ + gp_s];

    // pipeline registers: two corner sets (ping-pong)
    float aA00, aA01, aA10, aA11;
    float aB00, aB01, aB10, aB11;
    uint4 cA0[2], cA1[2], cA2[2], cA3[2];
    uint4 cB0[2], cB1[2], cB2[2], cB3[2];

    // prologue: issue tap kstart into set A, roll offsets to kstart+1
    ISSUE_TAP(kstart, dy, dx, mm, aA00, aA01, aA10, aA11, cA0, cA1, cA2, cA3);
    LOAD_OFF(kstart + 1);

#pragma unroll 1
    for (int k = kstart; k < kend; k += 2) {
        if (k + 1 < kend) {
            ISSUE_TAP(k + 1, dy, dx, mm, aB00, aB01, aB10, aB11, cB0, cB1, cB2, cB3);
            LOAD_OFF(k + 2);
        }
        CONSUME_TAP(k, aA00, aA01, aA10, aA11, cA0, cA1, cA2, cA3);
        if (k + 1 < kend) {
            if (k + 2 < kend) {
                ISSUE_TAP(k + 2, dy, dx, mm, aA00, aA01, aA10, aA11, cA0, cA1, cA2, cA3);
                LOAD_OFF(k + 3);
            }
            CONSUME_TAP(k + 1, aB00, aB01, aB10, aB11, cB0, cB1, cB2, cB3);
        }
    }

    // two-phase tree reduction (2-slot buffer)
    if (w >= 2) {
        float* rp = &red[((w - 2) * 64 + lane) * REDW];
#pragma unroll
        for (int ot = 0; ot < 4; ot++)
            *(float4*)&rp[ot * 4] = make_float4(acc[ot][0], acc[ot][1], acc[ot][2], acc[ot][3]);
    }
    __syncthreads();
    if (w < 2) {
        const float* rp = &red[(w * 64 + lane) * REDW];
#pragma unroll
        for (int ot = 0; ot < 4; ot++) {
            float4 v = *(const float4*)&rp[ot * 4];
            acc[ot][0] += v.x; acc[ot][1] += v.y;
            acc[ot][2] += v.z; acc[ot][3] += v.w;
        }
    }
    __syncthreads();
    if (w == 1) {
        float* rp = &red[lane * REDW];
#pragma unroll
        for (int ot = 0; ot < 4; ot++)
            *(float4*)&rp[ot * 4] = make_float4(acc[ot][0], acc[ot][1], acc[ot][2], acc[ot][3]);
    }
    __syncthreads();
    if (w == 0) {
        const float* rp = &red[lane * REDW];
#pragma unroll
        for (int ot = 0; ot < 4; ot++) {
            float4 v = *(const float4*)&rp[ot * 4];
            acc[ot][0] += v.x; acc[ot][1] += v.y;
            acc[ot][2] += v.z; acc[ot][3] += v.w;
        }
        int gp_m = gy * WW + gx0 + n;
#pragma unroll
        for (int ot = 0; ot < 4; ot++) {
            float4 rv = make_float4(acc[ot][0], acc[ot][1], acc[ot][2], acc[ot][3]);
            *(float4*)&rev[gp_m * 64 + ot * 16 + q * 4] = rv;
        }
    }
}

// ---------------------------------------------------------------------------
// k_fft: per 8x8 patch: proj_in via MFMA f16, then circular conv (fp32).
// Stages straight from f16 encH (plain 16B copies, no packing).
// ---------------------------------------------------------------------------
__global__ __launch_bounds__(256) void k_fft(
    const unsigned short* __restrict__ encH, const short* __restrict__ wpiA,
    const float* __restrict__ krT, float* __restrict__ e1)
{
    __shared__ __align__(16) short sbf[64 * SROW];   // f16 enc [px][c]
    __shared__ __align__(16) float e0[64 * ROWP];    // fp32 [px][o]
    int t = threadIdx.x;
    int pbx = blockIdx.x % 24, pby = blockIdx.x / 24;
    int gx0 = pbx * 8, gy0 = pby * 8;

#pragma unroll
    for (int r = 0; r < 2; r++) {
        int idx = t + r * 256;             // 512 x 8-ch units
        int px = idx >> 3, g8 = idx & 7;
        int gy = gy0 + (px >> 3), gx = gx0 + (px & 7);
        *(uint4*)&sbf[px * SROW + g8 * 8] =
            *(const uint4*)&encH[(gy * WW + gx) * 64 + g8 * 8];
    }
    __syncthreads();

    int lane = t & 63, w = t >> 6;
    int n = lane & 15, q = lane >> 4;
    h16x8 a0 = *(const h16x8*)&wpiA[(w * 2 + 0) * 512 + lane * 8];
    h16x8 a1 = *(const h16x8*)&wpiA[(w * 2 + 1) * 512 + lane * 8];
#pragma unroll
    for (int j = 0; j < 4; j++) {
        h16x8 b0 = *(const h16x8*)&sbf[(j * 16 + n) * SROW +  0 + q * 8];
        h16x8 b1 = *(const h16x8*)&sbf[(j * 16 + n) * SROW + 32 + q * 8];
        f32x4 acc = {0.f, 0.f, 0.f, 0.f};
        acc = __builtin_amdgcn_mfma_f32_16x16x32_f16(a0, b0, acc, 0, 0, 0);
        acc = __builtin_amdgcn_mfma_f32_16x16x32_f16(a1, b1, acc, 0, 0, 0);
#pragma unroll
        for (int r = 0; r < 4; r++)
            e0[(j * 16 + n) * ROWP + w * 16 + q * 4 + r] = acc[r];
    }
    __syncthreads();

    int o = t & 63;
    int yb = t >> 6;
#pragma unroll
    for (int yy = 0; yy < 2; yy++) {
        int y = yb + yy * 4;
        float outr[8];
#pragma unroll
        for (int x = 0; x < 8; x++) outr[x] = 0.f;
#pragma unroll
        for (int u = 0; u < 8; u++) {
            int ry = (y - u + 8) & 7;
            float row[8];
#pragma unroll
            for (int rx = 0; rx < 8; rx++)
                row[rx] = e0[(ry * 8 + rx) * ROWP + o];
#pragma unroll
            for (int v = 0; v < 8; v++) {
                float kv = krT[(u * 8 + v) * 64 + o];
#pragma unroll
                for (int x = 0; x < 8; x++)
                    outr[x] += kv * row[(x - v + 8) & 7];
            }
        }
        int gy = gy0 + y;
#pragma unroll
        for (int x = 0; x < 8; x++)
            e1[(gy * WW + gx0 + x) * 64 + o] = outr[x];
    }
}

// ---------------------------------------------------------------------------
// k_c3out: fused conv3x3(e1+rev) -> [.,dec] -> proj_out -> SimpleGate.
// ---------------------------------------------------------------------------
__global__ __launch_bounds__(256) void k_c3out(
    const float* __restrict__ e1, const float* __restrict__ rev,
    const short* __restrict__ w2A, const float* __restrict__ dec,
    const short* __restrict__ wpoA, float* __restrict__ out)
{
    __shared__ __align__(16) short sm[4][54 * C3ROW];  // per-wave: 3 rows x 18 px
    int t = threadIdx.x;
    int lane = t & 63, w = t >> 6;
    int b = blockIdx.x;
    int xcd = b & 7, blk = b >> 3;
    int gy  = xcd * 24 + blk / 3;
    int gx0 = (blk % 3) * 64 + w * 16;
    short* smw = &sm[w][0];
    int n = lane & 15, q = lane >> 4;

    for (int r = 0; r < 14; r++) {
        int u = lane + r * 64;
        if (u < 864) {
            int rp = u >> 4, g = u & 15;
            int row = rp / 18, pxl = rp - row * 18;
            int gyy = gy + row - 1, gxx = gx0 + pxl - 1;
            float4 v = make_float4(0.f, 0.f, 0.f, 0.f);
            if (gyy >= 0 && gyy < HH && gxx >= 0 && gxx < WW) {
                int gp = (gyy * WW + gxx) * 64 + g * 4;
                float4 va = *(const float4*)&e1[gp];
                float4 vb = *(const float4*)&rev[gp];
                v.x = va.x + vb.x; v.y = va.y + vb.y;
                v.z = va.z + vb.z; v.w = va.w + vb.w;
            }
            *(uint2*)&smw[rp * C3ROW + g * 4] = make_uint2(pkh(v.x, v.y), pkh(v.z, v.w));
        }
    }

    f32x4 acc[4];
#pragma unroll
    for (int ot = 0; ot < 4; ot++) acc[ot] = (f32x4){0.f, 0.f, 0.f, 0.f};

#pragma unroll 1
    for (int tap = 0; tap < 9; tap++) {
        int dy = tap / 3, dx = tap - dy * 3;
        int rp = dy * 18 + n + dx;
        h16x8 b0 = *(const h16x8*)&smw[rp * C3ROW +  0 + q * 8];
        h16x8 b1 = *(const h16x8*)&smw[rp * C3ROW + 32 + q * 8];
#pragma unroll
        for (int ot = 0; ot < 4; ot++) {
            h16x8 a0 = *(const h16x8*)&w2A[(tap * 8 + ot * 2 + 0) * 512 + lane * 8];
            h16x8 a1 = *(const h16x8*)&w2A[(tap * 8 + ot * 2 + 1) * 512 + lane * 8];
            acc[ot] = __builtin_amdgcn_mfma_f32_16x16x32_f16(a0, b0, acc[ot], 0, 0, 0);
            acc[ot] = __builtin_amdgcn_mfma_f32_16x16x32_f16(a1, b1, acc[ot], 0, 0, 0);
        }
    }

    // fused proj_out: stage e3 (C-layout regs) + dec into B-frag rows
#pragma unroll
    for (int ot = 0; ot < 4; ot++) {
        unsigned lo = pkh(acc[ot][0], acc[ot][1]);
        unsigned hi = pkh(acc[ot][2], acc[ot][3]);
        *(uint2*)&smw[n * OROW + ot * 16 + q * 4] = make_uint2(lo, hi);
    }
    {
        int gp = gy * WW + gx0 + n;
        unsigned pk[8];
#pragma unroll
        for (int i = 0; i < 8; i++) {
            float va = dec[(q * 16 + 2 * i)     * HWSZ + gp];
            float vb = dec[(q * 16 + 2 * i + 1) * HWSZ + gp];
            pk[i] = pkh(va, vb);
        }
        *(uint4*)&smw[n * OROW + 64 + q * 16]     = make_uint4(pk[0], pk[1], pk[2], pk[3]);
        *(uint4*)&smw[n * OROW + 64 + q * 16 + 8] = make_uint4(pk[4], pk[5], pk[6], pk[7]);
    }

    f32x4 go[8];
#pragma unroll
    for (int ot = 0; ot < 8; ot++) go[ot] = (f32x4){0.f, 0.f, 0.f, 0.f};

#pragma unroll 1
    for (int kt = 0; kt < 4; kt++) {
        h16x8 bb = *(const h16x8*)&smw[n * OROW + kt * 32 + q * 8];
#pragma unroll
        for (int ot = 0; ot < 8; ot++) {
            h16x8 aa = *(const h16x8*)&wpoA[(ot * 4 + kt) * 512 + lane * 8];
            go[ot] = __builtin_amdgcn_mfma_f32_16x16x32_f16(aa, bb, go[ot], 0, 0, 0);
        }
    }

    int gp = gy * WW + gx0 + n;
#pragma unroll
    for (int ot = 0; ot < 4; ot++)
#pragma unroll
        for (int r = 0; r < 4; r++)
            out[(ot * 16 + q * 4 + r) * HWSZ + gp] = go[ot][r] * go[ot + 4][r];
}

// ---------------------------------------------------------------------------
extern "C" void kernel_launch(void* const* d_in, const int* in_sizes, int n_in,
                              void* d_out, int out_size, void* d_ws, size_t ws_size,
                              hipStream_t stream)
{
    const float* enc  = (const float*)d_in[0];
    const float* dec  = (const float*)d_in[1];
    const float* ioff = (const float*)d_in[2];
    const float* iwt  = (const float*)d_in[3];
    const float* wpi  = (const float*)d_in[4];
    const float* fw   = (const float*)d_in[5];
    const float* wpo  = (const float*)d_in[6];
    const float* wd   = (const float*)d_in[7];
    const float* wc1  = (const float*)d_in[8];
    const float* wc2  = (const float*)d_in[9];
    float* out = (float*)d_out;
    float* ws  = (float*)d_ws;

    float*          krT  = ws;                           //    4096
    float*          rev  = ws + 4096;                    // 2359296  [px][64]
    float*          e1   = ws + 2363392;                 // 2359296  [px][64]
    unsigned short* encH = (unsigned short*)(ws + 4722688); // 2359296 f16 (1179648 fl)
    short*          wA   = (short*)(ws + 5902336);       // 200704 f16
    short*          w2A  = (short*)(ws + 6002688);       //  36864 f16
    short*          wpoA = (short*)(ws + 6021120);       //  16384 f16
    short*          wpiA = (short*)(ws + 6029312);       //   4096 f16

    hipLaunchKernelGGL(k_prep,   dim3(49),   dim3(256), 0, stream,
                       fw, wd, wc2, wc1, wpo, wpi, krT, wA, w2A, wpoA, wpiA);
    hipLaunchKernelGGL(k_trans,  dim3(576),  dim3(256), 0, stream, enc, encH);
    hipLaunchKernelGGL(k_deform, dim3(2304), dim3(256), 0, stream, encH, ioff, iwt, wA, rev);
    hipLaunchKernelGGL(k_fft,    dim3(576),  dim3(256), 0, stream, encH, wpiA, krT, e1);
    hipLaunchKernelGGL(k_c3out,  dim3(576),  dim3(256), 0, stream, e1, rev, w2A, dec, wpoA, out);
}

// Round 10
// 189.786 us; speedup vs baseline: 1.1907x; 1.1907x over previous
//
#include <hip/hip_runtime.h>
#include <math.h>

#define CH    64
#define WW    192
#define HH    192
#define HWSZ  (192*192)
#define KK    49
#define ROWP  68   // padded fp32 LDS row (dwords)
#define SROW  72   // f16 row stride in shorts (144B)
#define C3ROW 72   // conv3 staged px stride (shorts)
#define OROW  136  // k_out staged px stride (shorts, 128ch + 8 pad)

typedef __attribute__((ext_vector_type(8))) short     s16x8;
typedef __attribute__((ext_vector_type(8))) _Float16  h16x8;  // 8 f16 = 4 VGPR
typedef __attribute__((ext_vector_type(2))) _Float16  h16x2;
typedef __attribute__((ext_vector_type(2))) __fp16    fp16x2; // cvt_pkrtz result type
typedef __attribute__((ext_vector_type(4))) float     f32x4;

__device__ __forceinline__ unsigned short f2h(float f) {
    union { _Float16 h; unsigned short s; } u; u.h = (_Float16)f;  // RNE
    return u.s;
}

__device__ __forceinline__ float h2f(unsigned short s) {
    union { unsigned short s; _Float16 h; } u; u.s = s;
    return (float)u.h;
}

// pack two floats to f16x2 (RTZ, single v_cvt_pkrtz_f16_f32)
__device__ __forceinline__ unsigned pkh(float lo, float hi) {
    union { fp16x2 h; unsigned u; } v;
    v.h = __builtin_amdgcn_cvt_pkrtz(lo, hi);
    return v.u;
}

// broadcast one float into packed f16x2 (for pk_fma weights)
__device__ __forceinline__ h16x2 cvt2h(float a) {
    union { fp16x2 h; h16x2 o; } v;
    v.h = __builtin_amdgcn_cvt_pkrtz(a, a);
    return v.o;
}

__device__ __forceinline__ h16x2 as_h2(unsigned u) {
    union { unsigned u; h16x2 h; } v; v.u = u; return v.h;
}

__device__ __forceinline__ unsigned as_u(h16x2 h) {
    union { h16x2 h; unsigned u; } v; v.h = h; return v.u;
}

// ---------------------------------------------------------------------------
// k_pt (grid 625): b<576 -> trans (enc fp32 [c][p] -> encH f16 [p][c]);
// b>=576 -> prep tap k=b-576 (krT + A-frag packs). Fused: one launch,
// prep's 49 blocks overlap trans.
// ---------------------------------------------------------------------------
__device__ const float c_cos8[8] = {
    1.f, 0.70710678118654752f, 0.f, -0.70710678118654752f,
   -1.f, -0.70710678118654752f, 0.f, 0.70710678118654752f };

__global__ __launch_bounds__(256) void k_pt(
    const float* __restrict__ enc,  // trans input
    unsigned short* __restrict__ encH,
    const float* __restrict__ fw,   // [64,1,1,8,5]
    const float* __restrict__ wd,   // [64,64,7,7]
    const float* __restrict__ w2,   // [64,64,3,3]
    const float* __restrict__ wc1,  // [64,64,1,1]
    const float* __restrict__ wpo,  // [128,128]
    const float* __restrict__ wpi,  // [64,64]
    float* __restrict__ krT,        // [64 uv][64 c]
    short* __restrict__ wA,         // [49*8*512]
    short* __restrict__ w2A,        // [9*8*512]
    short* __restrict__ wpoA,       // [32*512]
    short* __restrict__ wpiA)       // [8*512]
{
    __shared__ __align__(16) char smem_raw[2 * 64 * ROWP * 4];  // 34816 B
    int b = blockIdx.x;
    int t = threadIdx.x;

    if (b < 576) {
        // ---- trans ----
        float* s = (float*)smem_raw;           // 64*65 floats = 16640 B
        int base = b * 64;
#pragma unroll
        for (int r = 0; r < 16; r++) {
            int idx = t + r * 256;
            int p = idx & 63, c = idx >> 6;
            s[p * 65 + c] = enc[c * HWSZ + base + p];
        }
        __syncthreads();
#pragma unroll
        for (int r = 0; r < 8; r++) {
            int idx = t + r * 256;             // 2048 pair-units
            int pr = idx & 31, p = idx >> 5;   // pair 0..31, px 0..63
            ((unsigned*)encH)[(base + p) * 32 + pr] =
                pkh(s[p * 65 + 2 * pr], s[p * 65 + 2 * pr + 1]);
        }
        return;
    }

    // ---- prep ----
    int kb = b - 576;                          // 0..48
    int tid = kb * 256 + t;
    int nt  = 49 * 256;
    for (int u = tid; u < 64 * 64; u += nt) {
        int uv = u >> 6, c = u & 63;
        int uu = uv >> 3, v = uv & 7;
        float acc = 0.f;
        for (int ky = 0; ky < 8; ky++)
            for (int kx = 0; kx < 8; kx++) {
                float wv = (kx <= 4) ? fw[c * 40 + ky * 5 + kx]
                                     : fw[c * 40 + ((8 - ky) & 7) * 5 + (8 - kx)];
                acc += wv * c_cos8[(ky * uu + kx * v) & 7];
            }
        krT[uv * 64 + c] = acc * (1.f / 64.f);
    }
    for (int u = tid; u < 9 * 4096; u += nt) {
        int tap = u / 4096, rem = u & 4095;
        int o = rem >> 6, c = rem & 63;
        float v = w2[(o * 64 + c) * 9 + tap];
        int fi = tap * 8 + (o >> 4) * 2 + (c >> 5);
        int ln = ((c >> 3) & 3) * 16 + (o & 15);
        w2A[fi * 512 + ln * 8 + (c & 7)] = (short)f2h(v);
    }
    for (int u = tid; u < 128 * 128; u += nt) {
        int o = u >> 7, c = u & 127;
        int fi = (o >> 4) * 4 + (c >> 5);
        int ln = ((c >> 3) & 3) * 16 + (o & 15);
        wpoA[fi * 512 + ln * 8 + (c & 7)] = (short)f2h(wpo[u]);
    }
    for (int u = tid; u < 64 * 64; u += nt) {
        int o = u >> 6, c = u & 63;
        int fi = (o >> 4) * 2 + (c >> 5);
        int ln = ((c >> 3) & 3) * 16 + (o & 15);
        wpiA[fi * 512 + ln * 8 + (c & 7)] = (short)f2h(wpi[u]);
    }

    // ---- fold wc1 @ wd + pack: one block per tap kb ----
    float* wdk  = (float*)smem_raw;            // 64*ROWP floats
    float* wc1s = wdk + 64 * ROWP;             // 64*ROWP floats
#pragma unroll
    for (int r = 0; r < 16; r++) {
        int idx = t + r * 256;
        int o = idx >> 6, c = idx & 63;
        wdk [o * ROWP + c] = wd[(o * 64 + c) * KK + kb];
        wc1s[o * ROWP + c] = wc1[o * 64 + c];
    }
    __syncthreads();

    int ot = (t >> 4) * 4, cb = (t & 15) * 4;
    float a[4][4];
#pragma unroll
    for (int i = 0; i < 4; i++)
#pragma unroll
        for (int j = 0; j < 4; j++) a[i][j] = 0.f;
    for (int o = 0; o < 64; o++) {
        float wv_[4], sv_[4];
#pragma unroll
        for (int i = 0; i < 4; i++) wv_[i] = wc1s[(ot + i) * ROWP + o];
#pragma unroll
        for (int j = 0; j < 4; j++) sv_[j] = wdk[o * ROWP + cb + j];
#pragma unroll
        for (int i = 0; i < 4; i++)
#pragma unroll
            for (int j = 0; j < 4; j++) a[i][j] += wv_[i] * sv_[j];
    }
#pragma unroll
    for (int i = 0; i < 4; i++)
#pragma unroll
        for (int j = 0; j < 4; j++) {
            int o2 = ot + i, c = cb + j;
            int tt = o2 >> 4, m = o2 & 15;
            int kt = c >> 5, q = (c >> 3) & 3, jj = c & 7;
            int ln = q * 16 + m;
            wA[(kb * 8 + tt * 2 + kt) * 512 + ln * 8 + jj] = (short)f2h(a[i][j]);
        }
}

// ---------------------------------------------------------------------------
// k_dff (grid 2880): b<2304 -> deform (R12 structure, 77us floor); b>=2304 ->
// fft. Both depend only on k_pt outputs; fused so fft's VALU-dense blocks
// co-reside with latency-bound deform (both pipes <40% there) -- fft runs in
// deform's shadow. Shared LDS budget kept at 19456 B (deform unchanged; fft's
// e0 stored f16 to fit 18432). rev and e1 written f16 [px][64] -> halves
// k_c3out staging traffic.
// ---------------------------------------------------------------------------
#define REDW 20   // reduction row stride (floats): 80B, 16B-aligned

__global__ __launch_bounds__(256) void k_dff(
    const unsigned short* __restrict__ encH, const float* __restrict__ off,
    const float* __restrict__ msk, const short* __restrict__ wA,
    unsigned short* __restrict__ revH,
    const short* __restrict__ wpiA, const float* __restrict__ krT,
    unsigned short* __restrict__ e1H)
{
    __shared__ __align__(16) char smem_raw[19456];
    int t = threadIdx.x;
    int lane = t & 63, w = t >> 6;
    int b = blockIdx.x;

    if (b < 2304) {
        // ================= deform =================
        short* sm_base = (short*)smem_raw;                 // 4 x 16*SROW shorts
        float* red = (float*)(smem_raw + 4 * 16 * SROW * 2); // 2*64*REDW floats

        int xcd = b & 7, blk = b >> 3;          // 288 strips per xcd band
        int gy  = xcd * 24 + blk / 12;
        int gx0 = (blk % 12) * 16;

        int sp = lane >> 2, g = lane & 3;       // gather map: quad-coalesced
        int sgx  = gx0 + sp;
        int gp_s = gy * WW + sgx;
        int n = lane & 15, q = lane >> 4;       // B-frag read map
        short* smw = sm_base + w * (16 * SROW);

        f32x4 acc[4];
#pragma unroll
        for (int ot = 0; ot < 4; ot++) acc[ot] = (f32x4){0.f, 0.f, 0.f, 0.f};

        int kstart = (w == 0) ? 0 : 13 + (w - 1) * 12;
        int kend   = (w == 0) ? 13 : kstart + 12;

        float dy = off[(2 * kstart) * HWSZ + gp_s];
        float dx = off[(2 * kstart + 1) * HWSZ + gp_s];
        float mm = msk[kstart * HWSZ + gp_s];

#pragma unroll 1
        for (int k = kstart; k < kend; k++) {
            int ky = k / 7, kx = k % 7;
            float y = (float)(gy  - 3 + ky) + dy;
            float x = (float)(sgx - 3 + kx) + dx;
            float y0f = floorf(y), x0f = floorf(x);
            float wy = y - y0f, wx = x - x0f;
            int iy0 = (int)y0f, ix0 = (int)x0f;
            int iy1 = iy0 + 1, ix1 = ix0 + 1;
            bool vy0 = (iy0 >= 0) & (iy0 < HH);
            bool vy1 = (iy1 >= 0) & (iy1 < HH);
            bool vx0 = (ix0 >= 0) & (ix0 < WW);
            bool vx1 = (ix1 >= 0) & (ix1 < WW);
            int iy0c = min(max(iy0, 0), HH - 1), iy1c = min(max(iy1, 0), HH - 1);
            int ix0c = min(max(ix0, 0), WW - 1), ix1c = min(max(ix1, 0), WW - 1);
            float a00 = (vy0 & vx0) ? (1.f - wy) * (1.f - wx) * mm : 0.f;
            float a01 = (vy0 & vx1) ? (1.f - wy) * wx * mm : 0.f;
            float a10 = (vy1 & vx0) ? wy * (1.f - wx) * mm : 0.f;
            float a11 = (vy1 & vx1) ? wy * wx * mm : 0.f;

            // f16 corners: 16 ch per lane = 2x16B per corner (quad-coalesced)
            const unsigned short* b00p = encH + (iy0c * WW + ix0c) * 64 + g * 16;
            const unsigned short* b01p = encH + (iy0c * WW + ix1c) * 64 + g * 16;
            const unsigned short* b10p = encH + (iy1c * WW + ix0c) * 64 + g * 16;
            const unsigned short* b11p = encH + (iy1c * WW + ix1c) * 64 + g * 16;
            uint4 u00[2], u01[2], u10[2], u11[2];
            u00[0] = *(const uint4*)b00p;  u00[1] = *(const uint4*)(b00p + 8);
            u01[0] = *(const uint4*)b01p;  u01[1] = *(const uint4*)(b01p + 8);
            u10[0] = *(const uint4*)b10p;  u10[1] = *(const uint4*)(b10p + 8);
            u11[0] = *(const uint4*)b11p;  u11[1] = *(const uint4*)(b11p + 8);

            // prefetch next-tap offsets
            float dyn = 0.f, dxn = 0.f, mmn = 0.f;
            if (k + 1 < kend) {
                dyn = off[(2 * k + 2) * HWSZ + gp_s];
                dxn = off[(2 * k + 3) * HWSZ + gp_s];
                mmn = msk[(k + 1) * HWSZ + gp_s];
            }

            // A-frag loads (L2-hot, independent of samples)
            h16x8 af[8];
#pragma unroll
            for (int f = 0; f < 8; f++)
                af[f] = *(const h16x8*)&wA[(k * 8 + f) * 512 + lane * 8];

            // packed-f16 blend: 4 cvt + 32 v_pk_fma_f16; output already packed
            h16x2 w00 = cvt2h(a00);
            h16x2 w01 = cvt2h(a01);
            h16x2 w10 = cvt2h(a10);
            h16x2 w11 = cvt2h(a11);

            unsigned c00[8] = {u00[0].x, u00[0].y, u00[0].z, u00[0].w,
                               u00[1].x, u00[1].y, u00[1].z, u00[1].w};
            unsigned c01[8] = {u01[0].x, u01[0].y, u01[0].z, u01[0].w,
                               u01[1].x, u01[1].y, u01[1].z, u01[1].w};
            unsigned c10[8] = {u10[0].x, u10[0].y, u10[0].z, u10[0].w,
                               u10[1].x, u10[1].y, u10[1].z, u10[1].w};
            unsigned c11[8] = {u11[0].x, u11[0].y, u11[0].z, u11[0].w,
                               u11[1].x, u11[1].y, u11[1].z, u11[1].w};
            unsigned pk[8];
#pragma unroll
            for (int j = 0; j < 8; j++) {
                h16x2 r = as_h2(c00[j]) * w00;
                r = as_h2(c01[j]) * w01 + r;
                r = as_h2(c10[j]) * w10 + r;
                r = as_h2(c11[j]) * w11 + r;
                pk[j] = as_u(r);
            }
            *(uint4*)&smw[sp * SROW + g * 16]     = make_uint4(pk[0], pk[1], pk[2], pk[3]);
            *(uint4*)&smw[sp * SROW + g * 16 + 8] = make_uint4(pk[4], pk[5], pk[6], pk[7]);

            h16x8 b0 = *(const h16x8*)&smw[n * SROW +  0 + q * 8];
            h16x8 b1 = *(const h16x8*)&smw[n * SROW + 32 + q * 8];

#pragma unroll
            for (int ot = 0; ot < 4; ot++) {
                acc[ot] = __builtin_amdgcn_mfma_f32_16x16x32_f16(af[ot * 2],     b0, acc[ot], 0, 0, 0);
                acc[ot] = __builtin_amdgcn_mfma_f32_16x16x32_f16(af[ot * 2 + 1], b1, acc[ot], 0, 0, 0);
            }

            dy = dyn; dx = dxn; mm = mmn;
        }

        // two-phase tree reduction (2-slot buffer)
        if (w >= 2) {
            float* rp = &red[((w - 2) * 64 + lane) * REDW];
#pragma unroll
            for (int ot = 0; ot < 4; ot++)
                *(float4*)&rp[ot * 4] = make_float4(acc[ot][0], acc[ot][1], acc[ot][2], acc[ot][3]);
        }
        __syncthreads();
        if (w < 2) {
            const float* rp = &red[(w * 64 + lane) * REDW];
#pragma unroll
            for (int ot = 0; ot < 4; ot++) {
                float4 v = *(const float4*)&rp[ot * 4];
                acc[ot][0] += v.x; acc[ot][1] += v.y;
                acc[ot][2] += v.z; acc[ot][3] += v.w;
            }
        }
        __syncthreads();
        if (w == 1) {
            float* rp = &red[lane * REDW];
#pragma unroll
            for (int ot = 0; ot < 4; ot++)
                *(float4*)&rp[ot * 4] = make_float4(acc[ot][0], acc[ot][1], acc[ot][2], acc[ot][3]);
        }
        __syncthreads();
        if (w == 0) {
            const float* rp = &red[lane * REDW];
#pragma unroll
            for (int ot = 0; ot < 4; ot++) {
                float4 v = *(const float4*)&rp[ot * 4];
                acc[ot][0] += v.x; acc[ot][1] += v.y;
                acc[ot][2] += v.z; acc[ot][3] += v.w;
            }
            int gp_m = gy * WW + gx0 + n;
            // f16 rev: lane holds ch ot*16+q*4..+3 of pixel gp_m
#pragma unroll
            for (int ot = 0; ot < 4; ot++) {
                unsigned u0 = pkh(acc[ot][0], acc[ot][1]);
                unsigned u1 = pkh(acc[ot][2], acc[ot][3]);
                *(uint2*)&revH[gp_m * 64 + ot * 16 + q * 4] = make_uint2(u0, u1);
            }
        }
        return;
    }

    // ================= fft =================
    {
        short* sbf = (short*)smem_raw;                 // 64*SROW shorts, 9216 B
        short* e0H = (short*)(smem_raw + 64 * SROW * 2); // 64*SROW shorts f16, 9216 B

        int pb = b - 2304;
        int pbx = pb % 24, pby = pb / 24;
        int gx0 = pbx * 8, gy0 = pby * 8;

#pragma unroll
        for (int r = 0; r < 2; r++) {
            int idx = t + r * 256;             // 512 x 8-ch units
            int px = idx >> 3, g8 = idx & 7;
            int gy = gy0 + (px >> 3), gx = gx0 + (px & 7);
            *(uint4*)&sbf[px * SROW + g8 * 8] =
                *(const uint4*)&encH[(gy * WW + gx) * 64 + g8 * 8];
        }
        __syncthreads();

        int n = lane & 15, q = lane >> 4;
        h16x8 a0 = *(const h16x8*)&wpiA[(w * 2 + 0) * 512 + lane * 8];
        h16x8 a1 = *(const h16x8*)&wpiA[(w * 2 + 1) * 512 + lane * 8];
#pragma unroll
        for (int j = 0; j < 4; j++) {
            h16x8 b0 = *(const h16x8*)&sbf[(j * 16 + n) * SROW +  0 + q * 8];
            h16x8 b1 = *(const h16x8*)&sbf[(j * 16 + n) * SROW + 32 + q * 8];
            f32x4 acc = {0.f, 0.f, 0.f, 0.f};
            acc = __builtin_amdgcn_mfma_f32_16x16x32_f16(a0, b0, acc, 0, 0, 0);
            acc = __builtin_amdgcn_mfma_f32_16x16x32_f16(a1, b1, acc, 0, 0, 0);
            // f16 e0: lane writes ch w*16+q*4..+3 of px j*16+n
            unsigned u0 = pkh(acc[0], acc[1]);
            unsigned u1 = pkh(acc[2], acc[3]);
            *(unsigned*)&e0H[(j * 16 + n) * SROW + w * 16 + q * 4]     = u0;
            *(unsigned*)&e0H[(j * 16 + n) * SROW + w * 16 + q * 4 + 2] = u1;
        }
        __syncthreads();

        int o = t & 63;
        int yb = t >> 6;
#pragma unroll
        for (int yy = 0; yy < 2; yy++) {
            int y = yb + yy * 4;
            float outr[8];
#pragma unroll
            for (int x = 0; x < 8; x++) outr[x] = 0.f;
#pragma unroll
            for (int u = 0; u < 8; u++) {
                int ry = (y - u + 8) & 7;
                float row[8];
#pragma unroll
                for (int rx = 0; rx < 8; rx++)
                    row[rx] = h2f(((const unsigned short*)e0H)[(ry * 8 + rx) * SROW + o]);
#pragma unroll
                for (int v = 0; v < 8; v++) {
                    float kv = krT[(u * 8 + v) * 64 + o];
#pragma unroll
                    for (int x = 0; x < 8; x++)
                        outr[x] += kv * row[(x - v + 8) & 7];
                }
            }
            int gy = gy0 + y;
#pragma unroll
            for (int x = 0; x < 8; x++)
                e1H[(gy * WW + gx0 + x) * 64 + o] = f2h(outr[x]);
        }
    }
}

// ---------------------------------------------------------------------------
// k_c3out: fused conv3x3(e1+rev, both f16) -> [.,dec] -> proj_out ->
// SimpleGate. Staging bytes halved vs fp32 e1/rev; packing deleted.
// ---------------------------------------------------------------------------
__global__ __launch_bounds__(256) void k_c3out(
    const unsigned short* __restrict__ e1H, const unsigned short* __restrict__ revH,
    const short* __restrict__ w2A, const float* __restrict__ dec,
    const short* __restrict__ wpoA, float* __restrict__ out)
{
    __shared__ __align__(16) short sm[4][54 * C3ROW];  // per-wave: 3 rows x 18 px
    int t = threadIdx.x;
    int lane = t & 63, w = t >> 6;
    int b = blockIdx.x;
    int xcd = b & 7, blk = b >> 3;
    int gy  = xcd * 24 + blk / 3;
    int gx0 = (blk % 3) * 64 + w * 16;
    short* smw = &sm[w][0];
    int n = lane & 15, q = lane >> 4;

    for (int r = 0; r < 14; r++) {
        int u = lane + r * 64;
        if (u < 864) {
            int rp = u >> 4, g = u & 15;
            int row = rp / 18, pxl = rp - row * 18;
            int gyy = gy + row - 1, gxx = gx0 + pxl - 1;
            uint2 v = make_uint2(0u, 0u);
            if (gyy >= 0 && gyy < HH && gxx >= 0 && gxx < WW) {
                int gp = (gyy * WW + gxx) * 64 + g * 4;    // short index
                uint2 va = *(const uint2*)&e1H[gp];
                uint2 vb = *(const uint2*)&revH[gp];
                v.x = as_u(as_h2(va.x) + as_h2(vb.x));
                v.y = as_u(as_h2(va.y) + as_h2(vb.y));
            }
            *(uint2*)&smw[rp * C3ROW + g * 4] = v;
        }
    }

    f32x4 acc[4];
#pragma unroll
    for (int ot = 0; ot < 4; ot++) acc[ot] = (f32x4){0.f, 0.f, 0.f, 0.f};

#pragma unroll 1
    for (int tap = 0; tap < 9; tap++) {
        int dy = tap / 3, dx = tap - dy * 3;
        int rp = dy * 18 + n + dx;
        h16x8 b0 = *(const h16x8*)&smw[rp * C3ROW +  0 + q * 8];
        h16x8 b1 = *(const h16x8*)&smw[rp * C3ROW + 32 + q * 8];
#pragma unroll
        for (int ot = 0; ot < 4; ot++) {
            h16x8 a0 = *(const h16x8*)&w2A[(tap * 8 + ot * 2 + 0) * 512 + lane * 8];
            h16x8 a1 = *(const h16x8*)&w2A[(tap * 8 + ot * 2 + 1) * 512 + lane * 8];
            acc[ot] = __builtin_amdgcn_mfma_f32_16x16x32_f16(a0, b0, acc[ot], 0, 0, 0);
            acc[ot] = __builtin_amdgcn_mfma_f32_16x16x32_f16(a1, b1, acc[ot], 0, 0, 0);
        }
    }

    // fused proj_out: stage e3 (C-layout regs) + dec into B-frag rows
#pragma unroll
    for (int ot = 0; ot < 4; ot++) {
        unsigned lo = pkh(acc[ot][0], acc[ot][1]);
        unsigned hi = pkh(acc[ot][2], acc[ot][3]);
        *(uint2*)&smw[n * OROW + ot * 16 + q * 4] = make_uint2(lo, hi);
    }
    {
        int gp = gy * WW + gx0 + n;
        unsigned pk[8];
#pragma unroll
        for (int i = 0; i < 8; i++) {
            float va = dec[(q * 16 + 2 * i)     * HWSZ + gp];
            float vb = dec[(q * 16 + 2 * i + 1) * HWSZ + gp];
            pk[i] = pkh(va, vb);
        }
        *(uint4*)&smw[n * OROW + 64 + q * 16]     = make_uint4(pk[0], pk[1], pk[2], pk[3]);
        *(uint4*)&smw[n * OROW + 64 + q * 16 + 8] = make_uint4(pk[4], pk[5], pk[6], pk[7]);
    }

    f32x4 go[8];
#pragma unroll
    for (int ot = 0; ot < 8; ot++) go[ot] = (f32x4){0.f, 0.f, 0.f, 0.f};

#pragma unroll 1
    for (int kt = 0; kt < 4; kt++) {
        h16x8 bb = *(const h16x8*)&smw[n * OROW + kt * 32 + q * 8];
#pragma unroll
        for (int ot = 0; ot < 8; ot++) {
            h16x8 aa = *(const h16x8*)&wpoA[(ot * 4 + kt) * 512 + lane * 8];
            go[ot] = __builtin_amdgcn_mfma_f32_16x16x32_f16(aa, bb, go[ot], 0, 0, 0);
        }
    }

    int gp = gy * WW + gx0 + n;
#pragma unroll
    for (int ot = 0; ot < 4; ot++)
#pragma unroll
        for (int r = 0; r < 4; r++)
            out[(ot * 16 + q * 4 + r) * HWSZ + gp] = go[ot][r] * go[ot + 4][r];
}

// ---------------------------------------------------------------------------
extern "C" void kernel_launch(void* const* d_in, const int* in_sizes, int n_in,
                              void* d_out, int out_size, void* d_ws, size_t ws_size,
                              hipStream_t stream)
{
    const float* enc  = (const float*)d_in[0];
    const float* dec  = (const float*)d_in[1];
    const float* ioff = (const float*)d_in[2];
    const float* iwt  = (const float*)d_in[3];
    const float* wpi  = (const float*)d_in[4];
    const float* fw   = (const float*)d_in[5];
    const float* wpo  = (const float*)d_in[6];
    const float* wd   = (const float*)d_in[7];
    const float* wc1  = (const float*)d_in[8];
    const float* wc2  = (const float*)d_in[9];
    float* out = (float*)d_out;
    float* ws  = (float*)d_ws;

    float*          krT  = ws;                               //   4096 fl
    unsigned short* revH = (unsigned short*)(ws + 4096);     // 2359296 sh = 1179648 fl
    unsigned short* e1H  = (unsigned short*)(ws + 1183744);  // 2359296 sh
    unsigned short* encH = (unsigned short*)(ws + 2363392);  // 2359296 sh
    short*          wA   = (short*)(ws + 3543040);           // 200704 sh = 100352 fl
    short*          w2A  = (short*)(ws + 3643392);           //  36864 sh = 18432 fl
    short*          wpoA = (short*)(ws + 3661824);           //  16384 sh = 8192 fl
    short*          wpiA = (short*)(ws + 3670016);           //   4096 sh

    hipLaunchKernelGGL(k_pt,    dim3(625),  dim3(256), 0, stream,
                       enc, encH, fw, wd, wc2, wc1, wpo, wpi, krT, wA, w2A, wpoA, wpiA);
    hipLaunchKernelGGL(k_dff,   dim3(2880), dim3(256), 0, stream,
                       encH, ioff, iwt, wA, revH, wpiA, krT, e1H);
    hipLaunchKernelGGL(k_c3out, dim3(576),  dim3(256), 0, stream,
                       e1H, revH, w2A, dec, wpoA, out);
}